// Round 1
// baseline (205.555 us; speedup 1.0000x reference)
//
#include <hip/hip_runtime.h>
#include <hip/hip_bf16.h>
#include <stdint.h>

#define SEQ    2048
#define DM     512
#define NHEAD  8
#define HD     64
#define BATCH  4
#define MTOT   (BATCH*SEQ)   // 8192

typedef __attribute__((ext_vector_type(4))) float  f32x4;
typedef __attribute__((ext_vector_type(8))) short  bf16x8;
typedef __attribute__((ext_vector_type(8))) unsigned short u16x8;
typedef __attribute__((ext_vector_type(4))) unsigned short u16x4;
typedef __attribute__((ext_vector_type(4))) float  fl4;

__device__ __forceinline__ unsigned short f2bf(float f) {
  union { float f; unsigned u; } c; c.f = f;
  return (unsigned short)((c.u + 0x7fffu + ((c.u >> 16) & 1u)) >> 16);
}

__device__ __forceinline__ void load_lds16(const void* g, void* l) {
  __builtin_amdgcn_global_load_lds((__attribute__((address_space(1))) void*)g,
                                   (__attribute__((address_space(3))) void*)l,
                                   16, 0, 0);
}

// ---------------- cast f32 -> bf16 (vectorized) ----------------
__global__ void k_cast_bf16(const float* __restrict__ src,
                            unsigned short* __restrict__ dst, int n4) {
  int i = blockIdx.x * 256 + threadIdx.x;
  if (i >= n4) return;
  fl4 v = *(const fl4*)(src + (size_t)i * 4);
  u16x4 o;
  o[0] = f2bf(v[0]); o[1] = f2bf(v[1]); o[2] = f2bf(v[2]); o[3] = f2bf(v[3]);
  *(u16x4*)(dst + (size_t)i * 4) = o;
}

// ---------------- transpose + cast: Wt[n][k] = W[k][n] ----------------
__global__ void k_transpose_cast(const float* __restrict__ W,
                                 unsigned short* __restrict__ Wt,
                                 int Kd, int Nd) {
  __shared__ __align__(16) unsigned short t[64][65];
  int k0 = blockIdx.y * 64, n0 = blockIdx.x * 64;
  int tid = threadIdx.x;
  int r = tid >> 2, cs = (tid & 3) * 16;
  const float* src = W + (size_t)(k0 + r) * Nd + n0 + cs;
#pragma unroll
  for (int i = 0; i < 4; ++i) {
    fl4 v = *(const fl4*)(src + i * 4);
    t[r][cs + i*4 + 0] = f2bf(v[0]);
    t[r][cs + i*4 + 1] = f2bf(v[1]);
    t[r][cs + i*4 + 2] = f2bf(v[2]);
    t[r][cs + i*4 + 3] = f2bf(v[3]);
  }
  __syncthreads();
  unsigned short* drow = Wt + (size_t)(n0 + r) * Kd + k0 + cs;
#pragma unroll
  for (int half = 0; half < 2; ++half) {
    u16x8 o;
#pragma unroll
    for (int i = 0; i < 8; ++i) o[i] = t[cs + half*8 + i][r];
    *(u16x8*)(drow + half * 8) = o;
  }
}

// ---------------- GEMM: C = A[M,K] @ Bt[N,K]^T + bias (+res) ----------------
// 128x128 tile, BK=64, 256 threads (4 waves as 2x2 of 64x64).
template<int RESID>
__global__ void k_gemm_bt(const unsigned short* __restrict__ A,
                          const unsigned short* __restrict__ Bt,
                          const float* __restrict__ bias,
                          const float* __restrict__ res,
                          void* __restrict__ Cout,
                          int M, int N, int K) {
  __shared__ __align__(16) unsigned short Als[128 * 64];
  __shared__ __align__(16) unsigned short Bls[128 * 64];
  int tid  = threadIdx.x;
  int lane = tid & 63, wave = tid >> 6;
  int lr = lane & 15, lk = lane >> 4;
  int wr = wave >> 1, wc = wave & 1;
  int m0 = blockIdx.y * 128, n0 = blockIdx.x * 128;
  f32x4 acc[4][4];
#pragma unroll
  for (int mt = 0; mt < 4; ++mt)
#pragma unroll
    for (int nt = 0; nt < 4; ++nt) acc[mt][nt] = f32x4{0.f, 0.f, 0.f, 0.f};

  int nkb = K >> 6;
  for (int kb = 0; kb < nkb; ++kb) {
    __syncthreads();
#pragma unroll
    for (int it = 0; it < 4; ++it) {
      int idx = tid + it * 256;
      int row = idx >> 3, ch = idx & 7;
      int sc = ch ^ (row & 7);   // pre-swizzled global source -> linear LDS dest
      load_lds16(A + (size_t)(m0 + row) * K + kb * 64 + sc * 8,
                 (char*)Als + idx * 16);
      load_lds16(Bt + (size_t)(n0 + row) * K + kb * 64 + sc * 8,
                 (char*)Bls + idx * 16);
    }
    __syncthreads();
#pragma unroll
    for (int ks = 0; ks < 2; ++ks) {
      bf16x8 a[4], b[4];
#pragma unroll
      for (int mt = 0; mt < 4; ++mt) {
        int row = wr * 64 + mt * 16 + lr;
        a[mt] = *(const bf16x8*)((char*)Als + row * 128 + (((ks*4 + lk) ^ (row & 7)) * 16));
      }
#pragma unroll
      for (int nt = 0; nt < 4; ++nt) {
        int row = wc * 64 + nt * 16 + lr;
        b[nt] = *(const bf16x8*)((char*)Bls + row * 128 + (((ks*4 + lk) ^ (row & 7)) * 16));
      }
#pragma unroll
      for (int mt = 0; mt < 4; ++mt)
#pragma unroll
        for (int nt = 0; nt < 4; ++nt)
          acc[mt][nt] = __builtin_amdgcn_mfma_f32_16x16x32_bf16(a[mt], b[nt], acc[mt][nt], 0, 0, 0);
    }
  }
  // epilogue: C/D layout col=lane&15, row=(lane>>4)*4+reg
#pragma unroll
  for (int nt = 0; nt < 4; ++nt) {
    int col = n0 + wc * 64 + nt * 16 + lr;
    float bv = bias[col];
#pragma unroll
    for (int mt = 0; mt < 4; ++mt) {
      int rowb = m0 + wr * 64 + mt * 16 + lk * 4;
#pragma unroll
      for (int rr = 0; rr < 4; ++rr) {
        float v = acc[mt][nt][rr] + bv;
        size_t off = (size_t)(rowb + rr) * N + col;
        if (RESID) ((float*)Cout)[off] = v + res[off];
        else       ((unsigned short*)Cout)[off] = f2bf(v);
      }
    }
  }
}

// ---------------- flash attention ----------------
// grid: 32 (b,h) * 32 q-tiles; block 256 = 4 waves * 16 q-rows; KVBLK=64
__global__ void k_attn(const unsigned short* __restrict__ Qb,
                       const unsigned short* __restrict__ KVb,
                       unsigned short* __restrict__ Ab) {
  __shared__ __align__(16) unsigned short Klds[64 * 64];
  __shared__ __align__(16) unsigned short Vtlds[64 * 64];
  __shared__ __align__(16) unsigned short Plds[4][16 * 64];
  int tid  = threadIdx.x;
  int lane = tid & 63, wave = tid >> 6;
  int lr = lane & 15, lk = lane >> 4;
  int bid = blockIdx.x;
  int qt = bid & 31, bh = bid >> 5;
  int b  = bh >> 3, h = bh & 7;
  int q0 = qt * 64 + wave * 16;
  size_t qrow = (size_t)b * SEQ + q0 + lr;
  bf16x8 qf0 = *(const bf16x8*)(Qb + qrow * DM + h * HD + lk * 8);
  bf16x8 qf1 = *(const bf16x8*)(Qb + qrow * DM + h * HD + 32 + lk * 8);
  f32x4 acc[4];
  float m[4], l[4];
#pragma unroll
  for (int i = 0; i < 4; ++i) { acc[i] = f32x4{0.f,0.f,0.f,0.f}; m[i] = -1e30f; l[i] = 0.0f; }
  const float scale = 0.125f;
  const size_t kvbase = (size_t)b * SEQ * 1024;
  int vp = tid >> 4, vcg = tid & 15;

  for (int kb = 0; kb < SEQ / 64; ++kb) {
    __syncthreads();
    // K tile: global_load_lds, source pre-swizzled, LDS linear
#pragma unroll
    for (int it = 0; it < 2; ++it) {
      int idx = tid + it * 256;
      int r = idx >> 3, ch = idx & 7;
      int sc = ch ^ (r & 7);
      load_lds16(KVb + kvbase + (size_t)(kb * 64 + r) * 1024 + h * HD + sc * 8,
                 (char*)Klds + idx * 16);
    }
    // V tile transposed into Vt[dv][token] (pack 2 adjacent tokens per b32)
#pragma unroll
    for (int vi = 0; vi < 2; ++vi) {
      int tokl = vi * 32 + 2 * vp;
      const unsigned short* vsrc = KVb + kvbase + (size_t)(kb * 64 + tokl) * 1024 + 512 + h * HD + vcg * 4;
      u16x4 va = *(const u16x4*)vsrc;
      u16x4 vb = *(const u16x4*)(vsrc + 1024);
#pragma unroll
      for (int i = 0; i < 4; ++i) {
        int c = vcg * 4 + i;
        int bir = tokl * 2;
        int swz = (bir >> 4) ^ (c & 7);
        *(unsigned*)((char*)Vtlds + c * 128 + swz * 16 + (bir & 15)) =
            (unsigned)va[i] | ((unsigned)vb[i] << 16);
      }
    }
    __syncthreads();

    // QK^T: scores[16q x 64k]
    f32x4 st[4];
#pragma unroll
    for (int kt = 0; kt < 4; ++kt) st[kt] = f32x4{0.f,0.f,0.f,0.f};
#pragma unroll
    for (int kt = 0; kt < 4; ++kt) {
      int row = kt * 16 + lr;
      bf16x8 kf0 = *(const bf16x8*)((char*)Klds + row * 128 + ((lk ^ (row & 7)) * 16));
      bf16x8 kf1 = *(const bf16x8*)((char*)Klds + row * 128 + (((4 + lk) ^ (row & 7)) * 16));
      st[kt] = __builtin_amdgcn_mfma_f32_16x16x32_bf16(qf0, kf0, st[kt], 0, 0, 0);
      st[kt] = __builtin_amdgcn_mfma_f32_16x16x32_bf16(qf1, kf1, st[kt], 0, 0, 0);
    }

    // online softmax (reduce over cols = 16-lane group x 4 tiles)
    float pv[4][4];
#pragma unroll
    for (int r = 0; r < 4; ++r) {
      float s0 = st[0][r] * scale, s1 = st[1][r] * scale;
      float s2 = st[2][r] * scale, s3 = st[3][r] * scale;
      float tm = fmaxf(fmaxf(s0, s1), fmaxf(s2, s3));
      tm = fmaxf(tm, __shfl_xor(tm, 1));
      tm = fmaxf(tm, __shfl_xor(tm, 2));
      tm = fmaxf(tm, __shfl_xor(tm, 4));
      tm = fmaxf(tm, __shfl_xor(tm, 8));
      float mn = fmaxf(m[r], tm);
      float corr = __expf(m[r] - mn);
      float p0 = __expf(s0 - mn), p1 = __expf(s1 - mn);
      float p2 = __expf(s2 - mn), p3 = __expf(s3 - mn);
      float rs = (p0 + p1) + (p2 + p3);
      rs += __shfl_xor(rs, 1);
      rs += __shfl_xor(rs, 2);
      rs += __shfl_xor(rs, 4);
      rs += __shfl_xor(rs, 8);
      l[r] = l[r] * corr + rs;
      m[r] = mn;
#pragma unroll
      for (int dt = 0; dt < 4; ++dt) acc[dt][r] *= corr;
      pv[0][r] = p0; pv[1][r] = p1; pv[2][r] = p2; pv[3][r] = p3;
    }

    // write P tile (bf16) to this wave's private LDS region (swizzled)
    char* pbase = (char*)Plds[wave];
#pragma unroll
    for (int kt = 0; kt < 4; ++kt)
#pragma unroll
      for (int r = 0; r < 4; ++r) {
        int row = lk * 4 + r, col = kt * 16 + lr;
        int swz = (col >> 3) ^ (row & 7);
        *(unsigned short*)(pbase + row * 128 + swz * 16 + (col & 7) * 2) = f2bf(pv[kt][r]);
      }

    // PV: out += P[16q x 64k] @ V[64k x 64dv]
#pragma unroll
    for (int ks = 0; ks < 2; ++ks) {
      bf16x8 pa = *(const bf16x8*)(pbase + lr * 128 + (((ks*4 + lk) ^ (lr & 7)) * 16));
#pragma unroll
      for (int dt = 0; dt < 4; ++dt) {
        int row = dt * 16 + lr;
        bf16x8 vf = *(const bf16x8*)((char*)Vtlds + row * 128 + (((ks*4 + lk) ^ (row & 7)) * 16));
        acc[dt] = __builtin_amdgcn_mfma_f32_16x16x32_bf16(pa, vf, acc[dt], 0, 0, 0);
      }
    }
  }

  // epilogue
#pragma unroll
  for (int dt = 0; dt < 4; ++dt) {
    int col = h * HD + dt * 16 + lr;
#pragma unroll
    for (int r = 0; r < 4; ++r) {
      size_t row = (size_t)b * SEQ + q0 + lk * 4 + r;
      Ab[row * DM + col] = f2bf(acc[dt][r] / l[r]);
    }
  }
}

// ---------------- LayerNorm (wave per row) ----------------
__global__ void k_ln(const float* __restrict__ x, const float* __restrict__ gamma,
                     const float* __restrict__ beta, float* __restrict__ out) {
  int tid = threadIdx.x, lane = tid & 63, wave = tid >> 6;
  size_t row = (size_t)blockIdx.x * 4 + wave;
  const float* xr = x + row * DM + lane * 8;
  fl4 v0 = *(const fl4*)xr;
  fl4 v1 = *(const fl4*)(xr + 4);
  float s  = (v0[0]+v0[1]) + (v0[2]+v0[3]) + (v1[0]+v1[1]) + (v1[2]+v1[3]);
  float ss = (v0[0]*v0[0]+v0[1]*v0[1]) + (v0[2]*v0[2]+v0[3]*v0[3])
           + (v1[0]*v1[0]+v1[1]*v1[1]) + (v1[2]*v1[2]+v1[3]*v1[3]);
#pragma unroll
  for (int off = 1; off < 64; off <<= 1) {
    s  += __shfl_xor(s, off);
    ss += __shfl_xor(ss, off);
  }
  float mu  = s * (1.0f / DM);
  float var = ss * (1.0f / DM) - mu * mu;
  float w = rsqrtf(var + 1e-5f);
  fl4 g0 = *(const fl4*)(gamma + lane*8), g1 = *(const fl4*)(gamma + lane*8 + 4);
  fl4 b0 = *(const fl4*)(beta + lane*8),  b1 = *(const fl4*)(beta + lane*8 + 4);
  fl4 o0, o1;
#pragma unroll
  for (int i = 0; i < 4; ++i) {
    o0[i] = (v0[i] - mu) * w * g0[i] + b0[i];
    o1[i] = (v1[i] - mu) * w * g1[i] + b1[i];
  }
  float* orow = out + row * DM + lane * 8;
  *(fl4*)orow = o0;
  *(fl4*)(orow + 4) = o1;
}

extern "C" void kernel_launch(void* const* d_in, const int* in_sizes, int n_in,
                              void* d_out, int out_size, void* d_ws, size_t ws_size,
                              hipStream_t stream) {
  const float* layer_input = (const float*)d_in[0];
  const float* cross       = (const float*)d_in[1];
  const float* Wq   = (const float*)d_in[2];
  const float* bq   = (const float*)d_in[3];
  const float* Wkv  = (const float*)d_in[4];
  const float* bkv  = (const float*)d_in[5];
  const float* Wo   = (const float*)d_in[6];
  const float* bo   = (const float*)d_in[7];
  const float* gamma = (const float*)d_in[8];
  const float* beta  = (const float*)d_in[9];
  float* out = (float*)d_out;

  char* ws = (char*)d_ws;
  unsigned short* Xb   = (unsigned short*)(ws + (size_t)0);
  unsigned short* Cb   = (unsigned short*)(ws + ((size_t)8  << 20));
  unsigned short* Qb   = (unsigned short*)(ws + ((size_t)16 << 20));
  unsigned short* KVb  = (unsigned short*)(ws + ((size_t)24 << 20));
  unsigned short* Abuf = (unsigned short*)(ws + ((size_t)40 << 20));
  float*          tmp  = (float*)         (ws + ((size_t)48 << 20));
  unsigned short* Wqt  = (unsigned short*)(ws + ((size_t)64 << 20));
  unsigned short* Wkvt = (unsigned short*)(ws + ((size_t)65 << 20));
  unsigned short* Wot  = (unsigned short*)(ws + ((size_t)67 << 20));

  // casts (activations)
  k_cast_bf16<<<(MTOT*DM/4 + 255)/256, 256, 0, stream>>>(layer_input, Xb, MTOT*DM/4);
  k_cast_bf16<<<(MTOT*DM/4 + 255)/256, 256, 0, stream>>>(cross, Cb, MTOT*DM/4);
  // weight transposes
  k_transpose_cast<<<dim3(8, 8),  256, 0, stream>>>(Wq,  Wqt,  512, 512);
  k_transpose_cast<<<dim3(16, 8), 256, 0, stream>>>(Wkv, Wkvt, 512, 1024);
  k_transpose_cast<<<dim3(8, 8),  256, 0, stream>>>(Wo,  Wot,  512, 512);
  // projections
  k_gemm_bt<0><<<dim3(4, 64), 256, 0, stream>>>(Xb, Wqt, bq, nullptr, Qb, MTOT, 512, 512);
  k_gemm_bt<0><<<dim3(8, 64), 256, 0, stream>>>(Cb, Wkvt, bkv, nullptr, KVb, MTOT, 1024, 512);
  // attention
  k_attn<<<1024, 256, 0, stream>>>(Qb, KVb, Abuf);
  // output projection + bias + residual (f32)
  k_gemm_bt<1><<<dim3(4, 64), 256, 0, stream>>>(Abuf, Wot, bo, layer_input, tmp, MTOT, 512, 512);
  // layernorm
  k_ln<<<MTOT/4, 256, 0, stream>>>(tmp, gamma, beta, out);
}

// Round 2
// 167.708 us; speedup vs baseline: 1.2257x; 1.2257x over previous
//
#include <hip/hip_runtime.h>
#include <hip/hip_bf16.h>
#include <stdint.h>

#define SEQ    2048
#define DM     512
#define NHEAD  8
#define HD     64
#define BATCH  4
#define MTOT   (BATCH*SEQ)   // 8192

typedef __attribute__((ext_vector_type(4))) float  f32x4;
typedef __attribute__((ext_vector_type(8))) short  bf16x8;
typedef __attribute__((ext_vector_type(8))) unsigned short u16x8;
typedef __attribute__((ext_vector_type(4))) unsigned short u16x4;
typedef __attribute__((ext_vector_type(4))) float  fl4;

__device__ __forceinline__ unsigned short f2bf(float f) {
  union { float f; unsigned u; } c; c.f = f;
  return (unsigned short)((c.u + 0x7fffu + ((c.u >> 16) & 1u)) >> 16);
}

__device__ __forceinline__ void load_lds16(const void* g, void* l) {
  __builtin_amdgcn_global_load_lds((__attribute__((address_space(1))) void*)g,
                                   (__attribute__((address_space(3))) void*)l,
                                   16, 0, 0);
}

// ---------------- cast f32 -> bf16 (vectorized) ----------------
__global__ void k_cast_bf16(const float* __restrict__ src,
                            unsigned short* __restrict__ dst, int n4) {
  int i = blockIdx.x * 256 + threadIdx.x;
  if (i >= n4) return;
  fl4 v = *(const fl4*)(src + (size_t)i * 4);
  u16x4 o;
  o[0] = f2bf(v[0]); o[1] = f2bf(v[1]); o[2] = f2bf(v[2]); o[3] = f2bf(v[3]);
  *(u16x4*)(dst + (size_t)i * 4) = o;
}

// ---------------- transpose + cast: Wt[n][k] = W[k][n] ----------------
__global__ void k_transpose_cast(const float* __restrict__ W,
                                 unsigned short* __restrict__ Wt,
                                 int Kd, int Nd) {
  __shared__ __align__(16) unsigned short t[64][65];
  int k0 = blockIdx.y * 64, n0 = blockIdx.x * 64;
  int tid = threadIdx.x;
  int r = tid >> 2, cs = (tid & 3) * 16;
  const float* src = W + (size_t)(k0 + r) * Nd + n0 + cs;
#pragma unroll
  for (int i = 0; i < 4; ++i) {
    fl4 v = *(const fl4*)(src + i * 4);
    t[r][cs + i*4 + 0] = f2bf(v[0]);
    t[r][cs + i*4 + 1] = f2bf(v[1]);
    t[r][cs + i*4 + 2] = f2bf(v[2]);
    t[r][cs + i*4 + 3] = f2bf(v[3]);
  }
  __syncthreads();
  unsigned short* drow = Wt + (size_t)(n0 + r) * Kd + k0 + cs;
#pragma unroll
  for (int half = 0; half < 2; ++half) {
    u16x8 o;
#pragma unroll
    for (int i = 0; i < 8; ++i) o[i] = t[cs + half*8 + i][r];
    *(u16x8*)(drow + half * 8) = o;
  }
}

// ---------------- GEMM: C = A[M,K] @ Bt[N,K]^T + bias (+res) ----------------
// 128x128 tile, BK=64, 256 threads (4 waves as 2x2 of 64x64).
template<int RESID>
__global__ void k_gemm_bt(const unsigned short* __restrict__ A,
                          const unsigned short* __restrict__ Bt,
                          const float* __restrict__ bias,
                          const float* __restrict__ res,
                          void* __restrict__ Cout,
                          int M, int N, int K) {
  __shared__ __align__(16) unsigned short Als[128 * 64];
  __shared__ __align__(16) unsigned short Bls[128 * 64];
  int tid  = threadIdx.x;
  int lane = tid & 63, wave = tid >> 6;
  int lr = lane & 15, lk = lane >> 4;
  int wr = wave >> 1, wc = wave & 1;
  int m0 = blockIdx.y * 128, n0 = blockIdx.x * 128;
  f32x4 acc[4][4];
#pragma unroll
  for (int mt = 0; mt < 4; ++mt)
#pragma unroll
    for (int nt = 0; nt < 4; ++nt) acc[mt][nt] = f32x4{0.f, 0.f, 0.f, 0.f};

  int nkb = K >> 6;
  for (int kb = 0; kb < nkb; ++kb) {
    __syncthreads();
#pragma unroll
    for (int it = 0; it < 4; ++it) {
      int idx = tid + it * 256;
      int row = idx >> 3, ch = idx & 7;
      int sc = ch ^ (row & 7);   // pre-swizzled global source -> linear LDS dest
      load_lds16(A + (size_t)(m0 + row) * K + kb * 64 + sc * 8,
                 (char*)Als + idx * 16);
      load_lds16(Bt + (size_t)(n0 + row) * K + kb * 64 + sc * 8,
                 (char*)Bls + idx * 16);
    }
    __syncthreads();
#pragma unroll
    for (int ks = 0; ks < 2; ++ks) {
      bf16x8 a[4], b[4];
#pragma unroll
      for (int mt = 0; mt < 4; ++mt) {
        int row = wr * 64 + mt * 16 + lr;
        a[mt] = *(const bf16x8*)((char*)Als + row * 128 + (((ks*4 + lk) ^ (row & 7)) * 16));
      }
#pragma unroll
      for (int nt = 0; nt < 4; ++nt) {
        int row = wc * 64 + nt * 16 + lr;
        b[nt] = *(const bf16x8*)((char*)Bls + row * 128 + (((ks*4 + lk) ^ (row & 7)) * 16));
      }
#pragma unroll
      for (int mt = 0; mt < 4; ++mt)
#pragma unroll
        for (int nt = 0; nt < 4; ++nt)
          acc[mt][nt] = __builtin_amdgcn_mfma_f32_16x16x32_bf16(a[mt], b[nt], acc[mt][nt], 0, 0, 0);
    }
  }
  // epilogue: C/D layout col=lane&15, row=(lane>>4)*4+reg
#pragma unroll
  for (int nt = 0; nt < 4; ++nt) {
    int col = n0 + wc * 64 + nt * 16 + lr;
    float bv = bias[col];
#pragma unroll
    for (int mt = 0; mt < 4; ++mt) {
      int rowb = m0 + wr * 64 + mt * 16 + lk * 4;
#pragma unroll
      for (int rr = 0; rr < 4; ++rr) {
        float v = acc[mt][nt][rr] + bv;
        size_t off = (size_t)(rowb + rr) * N + col;
        if (RESID) ((float*)Cout)[off] = v + res[off];
        else       ((unsigned short*)Cout)[off] = f2bf(v);
      }
    }
  }
}

// ---------------- flash attention (swapped-operand, in-register softmax) ----
// grid: 32 (b,h) * 32 q-tiles; block 256 = 4 waves * 16 q-rows; KVBLK=64
// S^T = mfma(K, Q): lane q = lane&15 holds S[q][t] for t = kt*16 + lk*4 + r.
// out^T = mfma(Vt, P): lane q = lane&15 holds out[q][d], d = dt*16 + lk*4 + r.
__global__ __launch_bounds__(256)
void k_attn(const unsigned short* __restrict__ Qb,
            const unsigned short* __restrict__ KVb,
            unsigned short* __restrict__ Ab) {
  __shared__ __align__(16) unsigned short Klds[64 * 64];
  __shared__ __align__(16) unsigned short Vtlds[64 * 64];
  __shared__ __align__(16) unsigned short Plds[4][16 * 64];
  int tid  = threadIdx.x;
  int lane = tid & 63, wave = tid >> 6;
  int q    = lane & 15, lk = lane >> 4;
  int bid = blockIdx.x;
  int qt = bid & 31, bh = bid >> 5;
  int b  = bh >> 3, h = bh & 7;
  int q0 = qt * 64 + wave * 16;
  size_t qrow = (size_t)b * SEQ + q0 + q;
  bf16x8 qf0 = *(const bf16x8*)(Qb + qrow * DM + h * HD + lk * 8);
  bf16x8 qf1 = *(const bf16x8*)(Qb + qrow * DM + h * HD + 32 + lk * 8);
  f32x4 acc[4];
#pragma unroll
  for (int i = 0; i < 4; ++i) acc[i] = f32x4{0.f,0.f,0.f,0.f};
  float m2 = -3e38f, l = 0.0f;              // running max (log2 domain), denom
  const float c1 = 0.125f * 1.44269504088896340736f;  // scale * log2(e)
  const size_t kvbase = (size_t)b * SEQ * 1024;
  int vp = tid >> 4, vcg = tid & 15;
  int sw = (q & 7) << 4;                    // P-lds XOR swizzle for this lane's row
  char* pbase = (char*)Plds[wave] + q * 128;

  for (int kb = 0; kb < SEQ / 64; ++kb) {
    __syncthreads();
    // K tile: global_load_lds, source pre-swizzled, LDS linear
#pragma unroll
    for (int it = 0; it < 2; ++it) {
      int idx = tid + it * 256;
      int r = idx >> 3, ch = idx & 7;
      int sc = ch ^ (r & 7);
      load_lds16(KVb + kvbase + (size_t)(kb * 64 + r) * 1024 + h * HD + sc * 8,
                 (char*)Klds + idx * 16);
    }
    // V tile transposed into Vt[dv][token] (pack 2 adjacent tokens per b32)
#pragma unroll
    for (int vi = 0; vi < 2; ++vi) {
      int tokl = vi * 32 + 2 * vp;
      const unsigned short* vsrc = KVb + kvbase + (size_t)(kb * 64 + tokl) * 1024 + 512 + h * HD + vcg * 4;
      u16x4 va = *(const u16x4*)vsrc;
      u16x4 vb = *(const u16x4*)(vsrc + 1024);
#pragma unroll
      for (int i = 0; i < 4; ++i) {
        int c = vcg * 4 + i;
        int bir = tokl * 2;
        int swz = (bir >> 4) ^ (c & 7);
        *(unsigned*)((char*)Vtlds + c * 128 + swz * 16 + (bir & 15)) =
            (unsigned)va[i] | ((unsigned)vb[i] << 16);
      }
    }
    __syncthreads();

    // QK^T swapped: st[kt] holds S^T[tok][q], tok = kt*16 + lk*4 + r, q = lane&15
    f32x4 st[4];
#pragma unroll
    for (int kt = 0; kt < 4; ++kt) st[kt] = f32x4{0.f,0.f,0.f,0.f};
#pragma unroll
    for (int kt = 0; kt < 4; ++kt) {
      int row = kt * 16 + q;
      bf16x8 kf0 = *(const bf16x8*)((char*)Klds + row * 128 + ((lk ^ (row & 7)) * 16));
      bf16x8 kf1 = *(const bf16x8*)((char*)Klds + row * 128 + (((4 + lk) ^ (row & 7)) * 16));
      st[kt] = __builtin_amdgcn_mfma_f32_16x16x32_bf16(kf0, qf0, st[kt], 0, 0, 0);
      st[kt] = __builtin_amdgcn_mfma_f32_16x16x32_bf16(kf1, qf1, st[kt], 0, 0, 0);
    }

    // in-register online softmax (lane-local row), exp2 domain
    float tm = fmaxf(fmaxf(st[0][0], st[0][1]), fmaxf(st[0][2], st[0][3]));
#pragma unroll
    for (int kt = 1; kt < 4; ++kt)
      tm = fmaxf(tm, fmaxf(fmaxf(st[kt][0], st[kt][1]), fmaxf(st[kt][2], st[kt][3])));
    tm *= c1;
    tm = fmaxf(tm, __shfl_xor(tm, 16));
    tm = fmaxf(tm, __shfl_xor(tm, 32));
    float mn = fmaxf(m2, tm);
    float corr = __builtin_amdgcn_exp2f(m2 - mn);
    m2 = mn;
    float p[4][4];
    float rs = 0.f;
#pragma unroll
    for (int kt = 0; kt < 4; ++kt) {
      float s0 = __builtin_amdgcn_exp2f(st[kt][0] * c1 - mn);
      float s1 = __builtin_amdgcn_exp2f(st[kt][1] * c1 - mn);
      float s2 = __builtin_amdgcn_exp2f(st[kt][2] * c1 - mn);
      float s3 = __builtin_amdgcn_exp2f(st[kt][3] * c1 - mn);
      p[kt][0] = s0; p[kt][1] = s1; p[kt][2] = s2; p[kt][3] = s3;
      rs += (s0 + s1) + (s2 + s3);
    }
    rs += __shfl_xor(rs, 16);
    rs += __shfl_xor(rs, 32);
    l = l * corr + rs;
#pragma unroll
    for (int dt = 0; dt < 4; ++dt) {
      acc[dt][0] *= corr; acc[dt][1] *= corr;
      acc[dt][2] *= corr; acc[dt][3] *= corr;
    }

    // pack P pairs to bf16x2 and store 8 dwords to this lane's P row (swizzled)
#pragma unroll
    for (int kt = 0; kt < 4; ++kt) {
#pragma unroll
      for (int j = 0; j < 2; ++j) {
        union { float f; unsigned u; } lo, hi;
        lo.f = p[kt][2*j]; hi.f = p[kt][2*j+1];
        unsigned pk = ((hi.u + 0x8000u) & 0xFFFF0000u) | ((lo.u + 0x8000u) >> 16);
        int off = (kt*32 + lk*8 + j*4) ^ sw;
        *(unsigned*)(pbase + off) = pk;
      }
    }

    // PV swapped: acc[dt] += mfma(Vt_frag, P_frag)
#pragma unroll
    for (int ks = 0; ks < 2; ++ks) {
      bf16x8 pb = *(const bf16x8*)(pbase + ((ks*64 + lk*16) ^ sw));
#pragma unroll
      for (int dt = 0; dt < 4; ++dt) {
        int row = dt * 16 + q;
        bf16x8 vf = *(const bf16x8*)((char*)Vtlds + row * 128 + (((ks*4 + lk) ^ (row & 7)) * 16));
        acc[dt] = __builtin_amdgcn_mfma_f32_16x16x32_bf16(vf, pb, acc[dt], 0, 0, 0);
      }
    }
  }

  // epilogue: lane q = lane&15 owns out[q0+q][:]; d = dt*16 + lk*4 + r
  float inv = 1.0f / l;
  size_t orow = ((size_t)b * SEQ + q0 + q) * DM + h * HD + lk * 4;
#pragma unroll
  for (int dt = 0; dt < 4; ++dt) {
    u16x4 o;
#pragma unroll
    for (int r = 0; r < 4; ++r) o[r] = f2bf(acc[dt][r] * inv);
    *(u16x4*)(Ab + orow + dt * 16) = o;
  }
}

// ---------------- LayerNorm (wave per row) ----------------
__global__ void k_ln(const float* __restrict__ x, const float* __restrict__ gamma,
                     const float* __restrict__ beta, float* __restrict__ out) {
  int tid = threadIdx.x, lane = tid & 63, wave = tid >> 6;
  size_t row = (size_t)blockIdx.x * 4 + wave;
  const float* xr = x + row * DM + lane * 8;
  fl4 v0 = *(const fl4*)xr;
  fl4 v1 = *(const fl4*)(xr + 4);
  float s  = (v0[0]+v0[1]) + (v0[2]+v0[3]) + (v1[0]+v1[1]) + (v1[2]+v1[3]);
  float ss = (v0[0]*v0[0]+v0[1]*v0[1]) + (v0[2]*v0[2]+v0[3]*v0[3])
           + (v1[0]*v1[0]+v1[1]*v1[1]) + (v1[2]*v1[2]+v1[3]*v1[3]);
#pragma unroll
  for (int off = 1; off < 64; off <<= 1) {
    s  += __shfl_xor(s, off);
    ss += __shfl_xor(ss, off);
  }
  float mu  = s * (1.0f / DM);
  float var = ss * (1.0f / DM) - mu * mu;
  float w = rsqrtf(var + 1e-5f);
  fl4 g0 = *(const fl4*)(gamma + lane*8), g1 = *(const fl4*)(gamma + lane*8 + 4);
  fl4 b0 = *(const fl4*)(beta + lane*8),  b1 = *(const fl4*)(beta + lane*8 + 4);
  fl4 o0, o1;
#pragma unroll
  for (int i = 0; i < 4; ++i) {
    o0[i] = (v0[i] - mu) * w * g0[i] + b0[i];
    o1[i] = (v1[i] - mu) * w * g1[i] + b1[i];
  }
  float* orow = out + row * DM + lane * 8;
  *(fl4*)orow = o0;
  *(fl4*)(orow + 4) = o1;
}

extern "C" void kernel_launch(void* const* d_in, const int* in_sizes, int n_in,
                              void* d_out, int out_size, void* d_ws, size_t ws_size,
                              hipStream_t stream) {
  const float* layer_input = (const float*)d_in[0];
  const float* cross       = (const float*)d_in[1];
  const float* Wq   = (const float*)d_in[2];
  const float* bq   = (const float*)d_in[3];
  const float* Wkv  = (const float*)d_in[4];
  const float* bkv  = (const float*)d_in[5];
  const float* Wo   = (const float*)d_in[6];
  const float* bo   = (const float*)d_in[7];
  const float* gamma = (const float*)d_in[8];
  const float* beta  = (const float*)d_in[9];
  float* out = (float*)d_out;

  char* ws = (char*)d_ws;
  unsigned short* Xb   = (unsigned short*)(ws + (size_t)0);
  unsigned short* Cb   = (unsigned short*)(ws + ((size_t)8  << 20));
  unsigned short* Qb   = (unsigned short*)(ws + ((size_t)16 << 20));
  unsigned short* KVb  = (unsigned short*)(ws + ((size_t)24 << 20));
  unsigned short* Abuf = (unsigned short*)(ws + ((size_t)40 << 20));
  float*          tmp  = (float*)         (ws + ((size_t)48 << 20));
  unsigned short* Wqt  = (unsigned short*)(ws + ((size_t)64 << 20));
  unsigned short* Wkvt = (unsigned short*)(ws + ((size_t)65 << 20));
  unsigned short* Wot  = (unsigned short*)(ws + ((size_t)67 << 20));

  // casts (activations)
  k_cast_bf16<<<(MTOT*DM/4 + 255)/256, 256, 0, stream>>>(layer_input, Xb, MTOT*DM/4);
  k_cast_bf16<<<(MTOT*DM/4 + 255)/256, 256, 0, stream>>>(cross, Cb, MTOT*DM/4);
  // weight transposes
  k_transpose_cast<<<dim3(8, 8),  256, 0, stream>>>(Wq,  Wqt,  512, 512);
  k_transpose_cast<<<dim3(16, 8), 256, 0, stream>>>(Wkv, Wkvt, 512, 1024);
  k_transpose_cast<<<dim3(8, 8),  256, 0, stream>>>(Wo,  Wot,  512, 512);
  // projections
  k_gemm_bt<0><<<dim3(4, 64), 256, 0, stream>>>(Xb, Wqt, bq, nullptr, Qb, MTOT, 512, 512);
  k_gemm_bt<0><<<dim3(8, 64), 256, 0, stream>>>(Cb, Wkvt, bkv, nullptr, KVb, MTOT, 1024, 512);
  // attention
  k_attn<<<1024, 256, 0, stream>>>(Qb, KVb, Abuf);
  // output projection + bias + residual (f32)
  k_gemm_bt<1><<<dim3(4, 64), 256, 0, stream>>>(Abuf, Wot, bo, layer_input, tmp, MTOT, 512, 512);
  // layernorm
  k_ln<<<MTOT/4, 256, 0, stream>>>(tmp, gamma, beta, out);
}

// Round 3
// 150.580 us; speedup vs baseline: 1.3651x; 1.1137x over previous
//
#include <hip/hip_runtime.h>
#include <hip/hip_bf16.h>
#include <stdint.h>

#define SEQ    2048
#define DM     512
#define NHEAD  8
#define HD     64
#define BATCH  4
#define MTOT   (BATCH*SEQ)   // 8192

typedef __attribute__((ext_vector_type(4))) float  f32x4;
typedef __attribute__((ext_vector_type(8))) short  bf16x8;
typedef __attribute__((ext_vector_type(8))) unsigned short u16x8;
typedef __attribute__((ext_vector_type(4))) unsigned short u16x4;
typedef __attribute__((ext_vector_type(4))) float  fl4;

__device__ __forceinline__ unsigned short f2bf(float f) {
  union { float f; unsigned u; } c; c.f = f;
  return (unsigned short)((c.u + 0x7fffu + ((c.u >> 16) & 1u)) >> 16);
}

__device__ __forceinline__ void load_lds16(const void* g, void* l) {
  __builtin_amdgcn_global_load_lds((__attribute__((address_space(1))) void*)g,
                                   (__attribute__((address_space(3))) void*)l,
                                   16, 0, 0);
}

// ---------------- cast f32 -> bf16 (two inputs, one launch) ----------------
__global__ void k_cast2_bf16(const float* __restrict__ s0, unsigned short* __restrict__ d0,
                             const float* __restrict__ s1, unsigned short* __restrict__ d1,
                             int n4) {
  int i = blockIdx.x * 256 + threadIdx.x;
  const float* src; unsigned short* dst;
  if (i >= n4) { i -= n4; src = s1; dst = d1; } else { src = s0; dst = d0; }
  fl4 v = *(const fl4*)(src + (size_t)i * 4);
  u16x4 o;
  o[0] = f2bf(v[0]); o[1] = f2bf(v[1]); o[2] = f2bf(v[2]); o[3] = f2bf(v[3]);
  *(u16x4*)(dst + (size_t)i * 4) = o;
}

// ---------------- transpose + cast: Wt[n][k] = W[k][n] ----------------
__global__ void k_transpose_cast(const float* __restrict__ W,
                                 unsigned short* __restrict__ Wt,
                                 int Kd, int Nd) {
  __shared__ __align__(16) unsigned short t[64][65];
  int k0 = blockIdx.y * 64, n0 = blockIdx.x * 64;
  int tid = threadIdx.x;
  int r = tid >> 2, cs = (tid & 3) * 16;
  const float* src = W + (size_t)(k0 + r) * Nd + n0 + cs;
#pragma unroll
  for (int i = 0; i < 4; ++i) {
    fl4 v = *(const fl4*)(src + i * 4);
    t[r][cs + i*4 + 0] = f2bf(v[0]);
    t[r][cs + i*4 + 1] = f2bf(v[1]);
    t[r][cs + i*4 + 2] = f2bf(v[2]);
    t[r][cs + i*4 + 3] = f2bf(v[3]);
  }
  __syncthreads();
  unsigned short* drow = Wt + (size_t)(n0 + r) * Kd + k0 + cs;
#pragma unroll
  for (int half = 0; half < 2; ++half) {
    u16x8 o;
#pragma unroll
    for (int i = 0; i < 8; ++i) o[i] = t[cs + half*8 + i][r];
    *(u16x8*)(drow + half * 8) = o;
  }
}

// ---------------- GEMM: C = A[M,K] @ Bt[N,K]^T + bias (+res) ----------------
template<int RESID>
__global__ void k_gemm_bt(const unsigned short* __restrict__ A,
                          const unsigned short* __restrict__ Bt,
                          const float* __restrict__ bias,
                          const float* __restrict__ res,
                          void* __restrict__ Cout,
                          int M, int N, int K) {
  __shared__ __align__(16) unsigned short Als[128 * 64];
  __shared__ __align__(16) unsigned short Bls[128 * 64];
  int tid  = threadIdx.x;
  int lane = tid & 63, wave = tid >> 6;
  int lr = lane & 15, lk = lane >> 4;
  int wr = wave >> 1, wc = wave & 1;
  int m0 = blockIdx.y * 128, n0 = blockIdx.x * 128;
  f32x4 acc[4][4];
#pragma unroll
  for (int mt = 0; mt < 4; ++mt)
#pragma unroll
    for (int nt = 0; nt < 4; ++nt) acc[mt][nt] = f32x4{0.f, 0.f, 0.f, 0.f};

  int nkb = K >> 6;
  for (int kb = 0; kb < nkb; ++kb) {
    __syncthreads();
#pragma unroll
    for (int it = 0; it < 4; ++it) {
      int idx = tid + it * 256;
      int row = idx >> 3, ch = idx & 7;
      int sc = ch ^ (row & 7);
      load_lds16(A + (size_t)(m0 + row) * K + kb * 64 + sc * 8,
                 (char*)Als + idx * 16);
      load_lds16(Bt + (size_t)(n0 + row) * K + kb * 64 + sc * 8,
                 (char*)Bls + idx * 16);
    }
    __syncthreads();
#pragma unroll
    for (int ks = 0; ks < 2; ++ks) {
      bf16x8 a[4], b[4];
#pragma unroll
      for (int mt = 0; mt < 4; ++mt) {
        int row = wr * 64 + mt * 16 + lr;
        a[mt] = *(const bf16x8*)((char*)Als + row * 128 + (((ks*4 + lk) ^ (row & 7)) * 16));
      }
#pragma unroll
      for (int nt = 0; nt < 4; ++nt) {
        int row = wc * 64 + nt * 16 + lr;
        b[nt] = *(const bf16x8*)((char*)Bls + row * 128 + (((ks*4 + lk) ^ (row & 7)) * 16));
      }
#pragma unroll
      for (int mt = 0; mt < 4; ++mt)
#pragma unroll
        for (int nt = 0; nt < 4; ++nt)
          acc[mt][nt] = __builtin_amdgcn_mfma_f32_16x16x32_bf16(a[mt], b[nt], acc[mt][nt], 0, 0, 0);
    }
  }
#pragma unroll
  for (int nt = 0; nt < 4; ++nt) {
    int col = n0 + wc * 64 + nt * 16 + lr;
    float bv = bias[col];
#pragma unroll
    for (int mt = 0; mt < 4; ++mt) {
      int rowb = m0 + wr * 64 + mt * 16 + lk * 4;
#pragma unroll
      for (int rr = 0; rr < 4; ++rr) {
        float v = acc[mt][nt][rr] + bv;
        size_t off = (size_t)(rowb + rr) * N + col;
        if (RESID) ((float*)Cout)[off] = v + res[off];
        else       ((unsigned short*)Cout)[off] = f2bf(v);
      }
    }
  }
}

// ---------------- flash attention, 32 q-rows/wave, double-buffered K/V ------
// grid: 32 (b,h) * 16 q-tiles(128); block 256 = 4 waves * 32 q-rows; KVBLK=64
// Swapped operands: S^T = mfma(K, Q); out^T = mfma(Vt, P). Lane q = lane&15
// owns rows {qh*16+q} of its wave's 32-row subtile, softmax fully in-register.
__global__ __launch_bounds__(256)
void k_attn(const unsigned short* __restrict__ Qb,
            const unsigned short* __restrict__ KVb,
            unsigned short* __restrict__ Ab) {
  __shared__ __align__(16) unsigned short Klds[2][64 * 64];
  __shared__ __align__(16) unsigned short Vtlds[2][64 * 64];
  __shared__ __align__(16) unsigned short Plds[4][32 * 64];
  int tid  = threadIdx.x;
  int lane = tid & 63, wave = tid >> 6;
  int q    = lane & 15, lk = lane >> 4;
  int bid = blockIdx.x;
  int qt = bid & 15, bh = bid >> 4;
  int b  = bh >> 3, h = bh & 7;
  int q0 = qt * 128 + wave * 32;
  const float c1 = 0.125f * 1.44269504088896340736f;  // scale * log2(e)
  const float THR = 11.5f;                            // defer-max threshold (log2)
  const size_t kvbase = (size_t)b * SEQ * 1024;
  int vp = tid >> 4, vcg = tid & 15;
  char* pwave = (char*)Plds[wave];

  // Q fragments: qf[qh][half]
  bf16x8 qf[2][2];
#pragma unroll
  for (int qh = 0; qh < 2; ++qh) {
    size_t qrow = (size_t)b * SEQ + q0 + qh * 16 + q;
    qf[qh][0] = *(const bf16x8*)(Qb + qrow * DM + h * HD + lk * 8);
    qf[qh][1] = *(const bf16x8*)(Qb + qrow * DM + h * HD + 32 + lk * 8);
  }
  f32x4 acc[2][4];
#pragma unroll
  for (int qh = 0; qh < 2; ++qh)
#pragma unroll
    for (int i = 0; i < 4; ++i) acc[qh][i] = f32x4{0.f,0.f,0.f,0.f};
  float m2[2] = {-3e38f, -3e38f}, l[2] = {0.f, 0.f};

  // ---- staging helpers (inlined by hand) ----
  // K stage (global_load_lds, pre-swizzled source):
#define STAGE_K(kb_, buf_) do {                                              \
    _Pragma("unroll")                                                        \
    for (int it = 0; it < 2; ++it) {                                         \
      int idx = tid + it * 256;                                              \
      int r_ = idx >> 3, ch_ = idx & 7;                                      \
      int sc_ = ch_ ^ (r_ & 7);                                              \
      load_lds16(KVb + kvbase + (size_t)((kb_) * 64 + r_) * 1024 + h * HD + sc_ * 8, \
                 (char*)Klds[buf_] + idx * 16);                              \
    } } while (0)
  // V load into regs:
#define LOAD_V(kb_, va_, vb_) do {                                           \
    _Pragma("unroll")                                                        \
    for (int vi = 0; vi < 2; ++vi) {                                         \
      int tokl = vi * 32 + 2 * vp;                                           \
      const unsigned short* vsrc = KVb + kvbase + (size_t)((kb_) * 64 + tokl) * 1024 + 512 + h * HD + vcg * 4; \
      va_[vi] = *(const u16x4*)vsrc;                                         \
      vb_[vi] = *(const u16x4*)(vsrc + 1024);                                \
    } } while (0)
  // V publish (transpose into Vt[dv][token], packed pairs):
#define STORE_V(buf_, va_, vb_) do {                                         \
    _Pragma("unroll")                                                        \
    for (int vi = 0; vi < 2; ++vi) {                                         \
      int tokl = vi * 32 + 2 * vp;                                           \
      _Pragma("unroll")                                                      \
      for (int i = 0; i < 4; ++i) {                                          \
        int c_ = vcg * 4 + i;                                                \
        int bir = tokl * 2;                                                  \
        int swz = (bir >> 4) ^ (c_ & 7);                                     \
        *(unsigned*)((char*)Vtlds[buf_] + c_ * 128 + swz * 16 + (bir & 15)) = \
            (unsigned)va_[vi][i] | ((unsigned)vb_[vi][i] << 16);             \
      } } } while (0)

  u16x4 va[2], vb[2];
  // prologue: stage tile 0 into buf 0
  STAGE_K(0, 0);
  LOAD_V(0, va, vb);
  STORE_V(0, va, vb);   // compiler inserts vmcnt wait for va/vb
  __syncthreads();      // also drains the K DMA

  int cur = 0;
  const int NT = SEQ / 64;
  for (int kb = 0; kb < NT; ++kb) {
    int nxt = kb + 1;
    // issue next tile's loads early (hide under compute)
    if (nxt < NT) {
      STAGE_K(nxt, cur ^ 1);
      LOAD_V(nxt, va, vb);
    }

    // ---- QK^T (swapped): st[qh][kt] holds S^T[tok][qrow] ----
    f32x4 st[2][4];
#pragma unroll
    for (int qh = 0; qh < 2; ++qh)
#pragma unroll
      for (int kt = 0; kt < 4; ++kt) st[qh][kt] = f32x4{0.f,0.f,0.f,0.f};
    __builtin_amdgcn_s_setprio(1);
#pragma unroll
    for (int kt = 0; kt < 4; ++kt) {
      int row = kt * 16 + q;
      bf16x8 kf0 = *(const bf16x8*)((char*)Klds[cur] + row * 128 + ((lk ^ (row & 7)) * 16));
      bf16x8 kf1 = *(const bf16x8*)((char*)Klds[cur] + row * 128 + (((4 + lk) ^ (row & 7)) * 16));
      st[0][kt] = __builtin_amdgcn_mfma_f32_16x16x32_bf16(kf0, qf[0][0], st[0][kt], 0, 0, 0);
      st[0][kt] = __builtin_amdgcn_mfma_f32_16x16x32_bf16(kf1, qf[0][1], st[0][kt], 0, 0, 0);
      st[1][kt] = __builtin_amdgcn_mfma_f32_16x16x32_bf16(kf0, qf[1][0], st[1][kt], 0, 0, 0);
      st[1][kt] = __builtin_amdgcn_mfma_f32_16x16x32_bf16(kf1, qf[1][1], st[1][kt], 0, 0, 0);
    }
    __builtin_amdgcn_s_setprio(0);

    // ---- online softmax (lane-local rows, exp2 domain, defer-max) ----
    float tm[2];
#pragma unroll
    for (int qh = 0; qh < 2; ++qh) {
      float t0 = fmaxf(fmaxf(st[qh][0][0], st[qh][0][1]), fmaxf(st[qh][0][2], st[qh][0][3]));
#pragma unroll
      for (int kt = 1; kt < 4; ++kt)
        t0 = fmaxf(t0, fmaxf(fmaxf(st[qh][kt][0], st[qh][kt][1]), fmaxf(st[qh][kt][2], st[qh][kt][3])));
      t0 *= c1;
      t0 = fmaxf(t0, __shfl_xor(t0, 16));
      t0 = fmaxf(t0, __shfl_xor(t0, 32));
      tm[qh] = t0;
    }
    if (!__all(tm[0] <= m2[0] + THR && tm[1] <= m2[1] + THR)) {
#pragma unroll
      for (int qh = 0; qh < 2; ++qh) {
        float mn = fmaxf(m2[qh], tm[qh]);
        float corr = __builtin_amdgcn_exp2f(m2[qh] - mn);
        m2[qh] = mn;
        l[qh] *= corr;
#pragma unroll
        for (int dt = 0; dt < 4; ++dt) {
          acc[qh][dt][0] *= corr; acc[qh][dt][1] *= corr;
          acc[qh][dt][2] *= corr; acc[qh][dt][3] *= corr;
        }
      }
    }
#pragma unroll
    for (int qh = 0; qh < 2; ++qh) {
      int prow = qh * 16 + q;
      int key = ((prow & 7) ^ (prow >> 3)) << 4;
      char* pbase = pwave + prow * 128;
      float rs = 0.f;
#pragma unroll
      for (int kt = 0; kt < 4; ++kt) {
        float p0 = __builtin_amdgcn_exp2f(st[qh][kt][0] * c1 - m2[qh]);
        float p1 = __builtin_amdgcn_exp2f(st[qh][kt][1] * c1 - m2[qh]);
        float p2 = __builtin_amdgcn_exp2f(st[qh][kt][2] * c1 - m2[qh]);
        float p3 = __builtin_amdgcn_exp2f(st[qh][kt][3] * c1 - m2[qh]);
        rs += (p0 + p1) + (p2 + p3);
        union { float f; unsigned u; } a0, a1, a2, a3;
        a0.f = p0; a1.f = p1; a2.f = p2; a3.f = p3;
        unsigned pk0 = ((a1.u + 0x8000u) & 0xFFFF0000u) | ((a0.u + 0x8000u) >> 16);
        unsigned pk1 = ((a3.u + 0x8000u) & 0xFFFF0000u) | ((a2.u + 0x8000u) >> 16);
        *(unsigned*)(pbase + ((kt*32 + lk*8 + 0) ^ key)) = pk0;
        *(unsigned*)(pbase + ((kt*32 + lk*8 + 4) ^ key)) = pk1;
      }
      rs += __shfl_xor(rs, 16);
      rs += __shfl_xor(rs, 32);
      l[qh] += rs;
    }

    // ---- PV (swapped): acc[qh][dt] += mfma(Vt_frag, P_frag) ----
    __builtin_amdgcn_s_setprio(1);
#pragma unroll
    for (int ks = 0; ks < 2; ++ks) {
      bf16x8 pb[2];
#pragma unroll
      for (int qh = 0; qh < 2; ++qh) {
        int prow = qh * 16 + q;
        int key = (prow & 7) ^ (prow >> 3);
        pb[qh] = *(const bf16x8*)(pwave + prow * 128 + (((ks*4 + lk) ^ key) * 16));
      }
#pragma unroll
      for (int dt = 0; dt < 4; ++dt) {
        int row = dt * 16 + q;
        bf16x8 vf = *(const bf16x8*)((char*)Vtlds[cur] + row * 128 + (((ks*4 + lk) ^ (row & 7)) * 16));
        acc[0][dt] = __builtin_amdgcn_mfma_f32_16x16x32_bf16(vf, pb[0], acc[0][dt], 0, 0, 0);
        acc[1][dt] = __builtin_amdgcn_mfma_f32_16x16x32_bf16(vf, pb[1], acc[1][dt], 0, 0, 0);
      }
    }
    __builtin_amdgcn_s_setprio(0);

    // publish next V tile, flip buffers
    if (nxt < NT) STORE_V(cur ^ 1, va, vb);
    __syncthreads();
    cur ^= 1;
  }

  // epilogue
#pragma unroll
  for (int qh = 0; qh < 2; ++qh) {
    float inv = 1.0f / l[qh];
    size_t orow = ((size_t)b * SEQ + q0 + qh * 16 + q) * DM + h * HD + lk * 4;
#pragma unroll
    for (int dt = 0; dt < 4; ++dt) {
      u16x4 o;
#pragma unroll
      for (int r = 0; r < 4; ++r) o[r] = f2bf(acc[qh][dt][r] * inv);
      *(u16x4*)(Ab + orow + dt * 16) = o;
    }
  }
#undef STAGE_K
#undef LOAD_V
#undef STORE_V
}

// ---------------- LayerNorm (wave per row) ----------------
__global__ void k_ln(const float* __restrict__ x, const float* __restrict__ gamma,
                     const float* __restrict__ beta, float* __restrict__ out) {
  int tid = threadIdx.x, lane = tid & 63, wave = tid >> 6;
  size_t row = (size_t)blockIdx.x * 4 + wave;
  const float* xr = x + row * DM + lane * 8;
  fl4 v0 = *(const fl4*)xr;
  fl4 v1 = *(const fl4*)(xr + 4);
  float s  = (v0[0]+v0[1]) + (v0[2]+v0[3]) + (v1[0]+v1[1]) + (v1[2]+v1[3]);
  float ss = (v0[0]*v0[0]+v0[1]*v0[1]) + (v0[2]*v0[2]+v0[3]*v0[3])
           + (v1[0]*v1[0]+v1[1]*v1[1]) + (v1[2]*v1[2]+v1[3]*v1[3]);
#pragma unroll
  for (int off = 1; off < 64; off <<= 1) {
    s  += __shfl_xor(s, off);
    ss += __shfl_xor(ss, off);
  }
  float mu  = s * (1.0f / DM);
  float var = ss * (1.0f / DM) - mu * mu;
  float w = rsqrtf(var + 1e-5f);
  fl4 g0 = *(const fl4*)(gamma + lane*8), g1 = *(const fl4*)(gamma + lane*8 + 4);
  fl4 b0 = *(const fl4*)(beta + lane*8),  b1 = *(const fl4*)(beta + lane*8 + 4);
  fl4 o0, o1;
#pragma unroll
  for (int i = 0; i < 4; ++i) {
    o0[i] = (v0[i] - mu) * w * g0[i] + b0[i];
    o1[i] = (v1[i] - mu) * w * g1[i] + b1[i];
  }
  float* orow = out + row * DM + lane * 8;
  *(fl4*)orow = o0;
  *(fl4*)(orow + 4) = o1;
}

extern "C" void kernel_launch(void* const* d_in, const int* in_sizes, int n_in,
                              void* d_out, int out_size, void* d_ws, size_t ws_size,
                              hipStream_t stream) {
  const float* layer_input = (const float*)d_in[0];
  const float* cross       = (const float*)d_in[1];
  const float* Wq   = (const float*)d_in[2];
  const float* bq   = (const float*)d_in[3];
  const float* Wkv  = (const float*)d_in[4];
  const float* bkv  = (const float*)d_in[5];
  const float* Wo   = (const float*)d_in[6];
  const float* bo   = (const float*)d_in[7];
  const float* gamma = (const float*)d_in[8];
  const float* beta  = (const float*)d_in[9];
  float* out = (float*)d_out;

  char* ws = (char*)d_ws;
  unsigned short* Xb   = (unsigned short*)(ws + (size_t)0);
  unsigned short* Cb   = (unsigned short*)(ws + ((size_t)8  << 20));
  unsigned short* Qb   = (unsigned short*)(ws + ((size_t)16 << 20));
  unsigned short* KVb  = (unsigned short*)(ws + ((size_t)24 << 20));
  unsigned short* Abuf = (unsigned short*)(ws + ((size_t)40 << 20));
  float*          tmp  = (float*)         (ws + ((size_t)48 << 20));
  unsigned short* Wqt  = (unsigned short*)(ws + ((size_t)64 << 20));
  unsigned short* Wkvt = (unsigned short*)(ws + ((size_t)65 << 20));
  unsigned short* Wot  = (unsigned short*)(ws + ((size_t)67 << 20));

  // casts (both activations in one launch)
  k_cast2_bf16<<<2 * (MTOT*DM/4) / 256, 256, 0, stream>>>(layer_input, Xb, cross, Cb, MTOT*DM/4);
  // weight transposes
  k_transpose_cast<<<dim3(8, 8),  256, 0, stream>>>(Wq,  Wqt,  512, 512);
  k_transpose_cast<<<dim3(16, 8), 256, 0, stream>>>(Wkv, Wkvt, 512, 1024);
  k_transpose_cast<<<dim3(8, 8),  256, 0, stream>>>(Wo,  Wot,  512, 512);
  // projections
  k_gemm_bt<0><<<dim3(4, 64), 256, 0, stream>>>(Xb, Wqt, bq, nullptr, Qb, MTOT, 512, 512);
  k_gemm_bt<0><<<dim3(8, 64), 256, 0, stream>>>(Cb, Wkvt, bkv, nullptr, KVb, MTOT, 1024, 512);
  // attention (512 blocks: 32 bh * 16 q-tiles of 128 rows)
  k_attn<<<512, 256, 0, stream>>>(Qb, KVb, Abuf);
  // output projection + bias + residual (f32)
  k_gemm_bt<1><<<dim3(4, 64), 256, 0, stream>>>(Abuf, Wot, bo, layer_input, tmp, MTOT, 512, 512);
  // layernorm
  k_ln<<<MTOT/4, 256, 0, stream>>>(tmp, gamma, beta, out);
}